// Round 1
// baseline (856.677 us; speedup 1.0000x reference)
//
#include <hip/hip_runtime.h>
#include <hip/hip_bf16.h>

// SelMul: out[b,o] = sum_{i<=j} x[b,i]*x[b,j]*W[o, idx(i,j)]
// B=256, D=512, OUT=1024, H=(D+1)*D/2=131328
//
// GEMM view: packed(256 x 131328) @ W^T, A-operand generated on the fly.
// Segment i (i=0..511): K-run [base_i, base_i + (512-i)), A[b,k] = x[b,i]*x[b,j]
// with j = i + (k - base_i). Scale x[b,i] deferred to per-segment epilogue.
//
// BM=256 (whole M -> W read exactly once from HBM: 538 MB, the roofline floor).
// Grid: 8 N-tiles x 32 K-split blocks. Split-K combined with fp32 atomicAdd
// after a zero-init kernel (harness poisons d_out with 0xAA).

#define DDIM 512
#define ODIM 1024
#define HDIM 131328
#define A_STRIDE 40   // 32 + 8 pad (bf16 elems); row stride 80B -> 2-way bank alias (free)
#define W_STRIDE 40

typedef __attribute__((ext_vector_type(8))) short short8;
typedef __attribute__((ext_vector_type(4))) float floatx4;

__global__ __launch_bounds__(256) void zero_out_kernel(float4* out) {
    out[blockIdx.x * 256 + threadIdx.x] = make_float4(0.f, 0.f, 0.f, 0.f);
}

__device__ inline unsigned short f2bf(float v) {
    __hip_bfloat16 h = __float2bfloat16(v);
    return __builtin_bit_cast(unsigned short, h);
}

__global__ __launch_bounds__(512, 2) void selmul_kernel(const float* __restrict__ x,
                                                        const float* __restrict__ W,
                                                        float* __restrict__ out) {
    __shared__ __align__(16) unsigned short A_lds[256 * A_STRIDE];
    __shared__ __align__(16) unsigned short W_lds[128 * W_STRIDE];
    __shared__ float sc[2][256];

    const int t    = threadIdx.x;
    const int lane = t & 63;
    const int wave = t >> 6;            // 0..7
    const int wm   = (wave >> 1) * 64;  // wave M offset (4 rows of waves)
    const int wn   = (wave & 1) * 64;   // wave N offset (2 cols of waves)
    const int l15  = lane & 15;
    const int quad = lane >> 4;         // 0..3

    const int n_tile = blockIdx.x;      // 0..7
    const int s      = blockIdx.y;      // 0..31 (k-split)
    const int n0     = n_tile * 128;

    // staging decomposition: thread handles fixed column jj, rows rbase+16e
    const int jj    = t & 31;
    const int rbase = t >> 5;           // 0..15

    floatx4 acc[4][4] = {};             // total accumulator (scaled)

    for (int tseg = 0; tseg < 16; ++tseg) {
        const int tt   = tseg >> 1;
        const int i    = (tseg & 1) ? (63 - s + 64 * tt) : (s + 64 * tt);
        const int len  = DDIM - i;
        const int base = i * DDIM - (i * (i - 1)) / 2;  // start of segment i in packed K
        const int steps = (len + 31) >> 5;
        const int buf  = tseg & 1;

        // stage fp32 scale column x[:, i] (read at segment epilogue; double-buffered
        // so no extra barrier needed vs previous segment's epilogue readers)
        if (t < 256) sc[buf][t] = x[t * DDIM + i];

        floatx4 accs[4][4] = {};        // per-segment (unscaled) accumulator

        for (int st = 0; st < steps; ++st) {
            const int j0 = i + st * 32;
            const int kc = base + st * 32;
            const bool valid = (j0 + jj) < DDIM;      // per-thread, step-uniform
            const int j  = valid ? (j0 + jj) : 0;     // safe x column
            const int ks = valid ? (kc + jj) : base;  // safe W column (value unused: A=0)

            // stage A tile: x[0:256, j0:j0+32] -> bf16 (zero-masked past column D)
            #pragma unroll
            for (int e = 0; e < 16; ++e) {
                const int m = rbase + 16 * e;
                float v = x[m * DDIM + j];
                v = valid ? v : 0.0f;
                A_lds[m * A_STRIDE + jj] = f2bf(v);
            }
            // stage W tile: W[n0:n0+128, kc:kc+32] -> bf16 (addr-clamped; A=0 masks value)
            #pragma unroll
            for (int e = 0; e < 8; ++e) {
                const int n = rbase + 16 * e;
                float v = W[(long)(n0 + n) * HDIM + ks];
                W_lds[n * W_STRIDE + jj] = f2bf(v);
            }
            __syncthreads();

            // fragments: A[m=lane&15][k=quad*8+e], B(=W rows)[n=lane&15][k=quad*8+e]
            short8 af[4], bw[4];
            #pragma unroll
            for (int fm = 0; fm < 4; ++fm)
                af[fm] = *(const short8*)&A_lds[(wm + fm * 16 + l15) * A_STRIDE + quad * 8];
            #pragma unroll
            for (int fn = 0; fn < 4; ++fn)
                bw[fn] = *(const short8*)&W_lds[(wn + fn * 16 + l15) * W_STRIDE + quad * 8];

            #pragma unroll
            for (int fm = 0; fm < 4; ++fm)
                #pragma unroll
                for (int fn = 0; fn < 4; ++fn)
                    accs[fm][fn] = __builtin_amdgcn_mfma_f32_16x16x32_bf16(
                        af[fm], bw[fn], accs[fm][fn], 0, 0, 0);
            __syncthreads();
        }

        // segment epilogue: acc_tot += x[m,i] * acc_seg   (fp32 scale)
        // C/D layout: row = quad*4 + r, col = lane&15  [m89/m91]
        #pragma unroll
        for (int fm = 0; fm < 4; ++fm) {
            #pragma unroll
            for (int r = 0; r < 4; ++r) {
                const float scale = sc[buf][wm + fm * 16 + quad * 4 + r];
                #pragma unroll
                for (int fn = 0; fn < 4; ++fn)
                    acc[fm][fn][r] += scale * accs[fm][fn][r];
            }
        }
    }

    // split-K combine: atomicAdd into zero-initialized out (fp32, device scope)
    #pragma unroll
    for (int fm = 0; fm < 4; ++fm) {
        const int row = wm + fm * 16 + quad * 4;
        #pragma unroll
        for (int fn = 0; fn < 4; ++fn) {
            const int col = n0 + wn + fn * 16 + l15;
            #pragma unroll
            for (int r = 0; r < 4; ++r)
                atomicAdd(&out[(row + r) * ODIM + col], acc[fm][fn][r]);
        }
    }
}

extern "C" void kernel_launch(void* const* d_in, const int* in_sizes, int n_in,
                              void* d_out, int out_size, void* d_ws, size_t ws_size,
                              hipStream_t stream) {
    const float* x = (const float*)d_in[0];   // (256, 512) fp32
    const float* W = (const float*)d_in[1];   // (1024, 131328) fp32
    float* out = (float*)d_out;               // (256, 1024) fp32

    // zero d_out (poisoned 0xAA by harness; atomics accumulate into it)
    hipLaunchKernelGGL(zero_out_kernel, dim3(256), dim3(256), 0, stream, (float4*)out);
    // 8 N-tiles x 32 k-split blocks = 256 blocks (1 per CU), 512 threads (8 waves)
    hipLaunchKernelGGL(selmul_kernel, dim3(8, 32), dim3(512), 0, stream, x, W, out);
}

// Round 3
// 852.075 us; speedup vs baseline: 1.0054x; 1.0054x over previous
//
#include <hip/hip_runtime.h>
#include <hip/hip_bf16.h>

// SelMul: out[b,o] = sum_{i<=j} x[b,i]*x[b,j]*W[o, idx(i,j)]
// B=256, D=512, OUT=1024, H=131328.
// GEMM: packed(256 x 131328) @ W^T with A generated on the fly.
// Segment i: K-run [base_i, base_i+512-i), A[b,k] = x[b,i]*x[b,j] (scale folded
// at staging). BM=256 -> W read exactly once (538 MB = 85us roofline floor).
// Memory-latency is the enemy: register-prefetch pipeline + raw s_barrier
// (no vmcnt drain) keeps next step's W loads in flight across the MFMA phase.
// Split-K partials go to ws (plain stores), summed by a reduce kernel.

#define DDIM 512
#define ODIM 1024
#define HDIM 131328L
#define NSPLIT 32
#define AST 40   // A LDS row stride (bf16): 32 + 8 pad; 80 B rows (16B-aligned)
#define WST 40

typedef __attribute__((ext_vector_type(4))) float floatx4;
typedef __attribute__((ext_vector_type(8))) short short8;
typedef floatx4 __attribute__((aligned(4))) floatx4u;   // allow 4B-aligned dwordx4

__device__ inline floatx4 load4u(const float* p) { return *(const floatx4u*)p; }

__device__ inline unsigned short f2bf(float v) {
    return __builtin_bit_cast(unsigned short, __float2bfloat16(v));
}

__device__ inline unsigned f2bf2(float a, float b) {
    // pack two bf16 into one dword (bfloat162 isn't trivially copyable -> manual)
    return (unsigned)f2bf(a) | ((unsigned)f2bf(b) << 16);
}

// Raw barriers: do NOT drain vmcnt (prefetch stays in flight).
#define BAR_PLAIN() asm volatile("s_barrier" ::: "memory")
#define BAR_LGKM()  asm volatile("s_waitcnt lgkmcnt(0)\n\ts_barrier" ::: "memory")

__global__ __launch_bounds__(512, 2) void selmul_kernel(const float* __restrict__ x,
                                                        const float* __restrict__ W,
                                                        float* __restrict__ part) {
    __shared__ __align__(16) unsigned short A_lds[256 * AST];
    __shared__ __align__(16) unsigned short W_lds[128 * WST];

    const int t    = threadIdx.x;
    const int lane = t & 63;
    const int wave = t >> 6;            // 0..7
    const int wm   = (wave >> 1) * 64;  // 4 wave-rows
    const int wn   = (wave & 1) * 64;   // 2 wave-cols
    const int l15  = lane & 15;
    const int quad = lane >> 4;

    const int n0 = blockIdx.x * 128;    // 8 N-tiles
    const int s  = blockIdx.y;          // 0..31 k-split

    // vector staging decomposition: 4-col group c4, base row rv
    const int c4 = t & 7;               // cols c4*4 .. +3
    const int rv = t >> 3;              // 0..63

    floatx4 acc[4][4] = {};
    floatx4 av[4], wv[2];
    float   xi[4];

    auto mfma_phase = [&]() {
        short8 af[4], bw[4];
        #pragma unroll
        for (int fm = 0; fm < 4; ++fm)
            af[fm] = *(const short8*)&A_lds[(wm + fm * 16 + l15) * AST + quad * 8];
        #pragma unroll
        for (int fn = 0; fn < 4; ++fn)
            bw[fn] = *(const short8*)&W_lds[(wn + fn * 16 + l15) * WST + quad * 8];
        #pragma unroll
        for (int fm = 0; fm < 4; ++fm)
            #pragma unroll
            for (int fn = 0; fn < 4; ++fn)
                acc[fm][fn] = __builtin_amdgcn_mfma_f32_16x16x32_bf16(
                    af[fm], bw[fn], acc[fm][fn], 0, 0, 0);
    };

    for (int tseg = 0; tseg < 16; ++tseg) {
        const int tt   = tseg >> 1;
        const int i    = (tseg & 1) ? (63 - s + 64 * tt) : (s + 64 * tt);
        const int len  = DDIM - i;
        const long base = (long)i * DDIM - (long)i * (i - 1) / 2;
        const int full = len >> 5;      // mask-free 32-col steps
        const int rem  = len & 31;      // masked tail columns

        // per-segment scale column, rows rv+64e (L2-hot scalar loads)
        #pragma unroll
        for (int e = 0; e < 4; ++e)
            xi[e] = x[(rv + 64 * e) * DDIM + i];

        if (full > 0) {
            const float* axp = x + rv * DDIM + i + c4 * 4;
            const float* wpp = W + (long)(n0 + rv) * HDIM + base + c4 * 4;
            // prefetch step 0 (A first: L2-fast, consumed first; W: HBM)
            #pragma unroll
            for (int e = 0; e < 4; ++e) av[e] = load4u(axp + e * 64 * DDIM);
            #pragma unroll
            for (int e = 0; e < 2; ++e) wv[e] = load4u(wpp + (long)e * 64 * HDIM);
            axp += 32; wpp += 32;

            for (int st = 0; st < full; ++st) {
                BAR_PLAIN();   // prev MFMA phase's LDS reads have landed (lgkm waits)
                // ---- store phase: convert prefetched regs -> LDS (waits vmcnt here)
                #pragma unroll
                for (int e = 0; e < 4; ++e) {
                    const int row = rv + 64 * e;
                    floatx4 v = av[e];
                    const float sc = xi[e];
                    uint2 p;
                    p.x = f2bf2(v.x * sc, v.y * sc);
                    p.y = f2bf2(v.z * sc, v.w * sc);
                    *(uint2*)&A_lds[row * AST + c4 * 4] = p;
                }
                #pragma unroll
                for (int e = 0; e < 2; ++e) {
                    const int row = rv + 64 * e;
                    floatx4 v = wv[e];
                    uint2 p;
                    p.x = f2bf2(v.x, v.y);
                    p.y = f2bf2(v.z, v.w);
                    *(uint2*)&W_lds[row * WST + c4 * 4] = p;
                }
                // ---- issue next step's loads; they stay in flight through MFMA
                if (st + 1 < full) {
                    #pragma unroll
                    for (int e = 0; e < 4; ++e) av[e] = load4u(axp + e * 64 * DDIM);
                    #pragma unroll
                    for (int e = 0; e < 2; ++e) wv[e] = load4u(wpp + (long)e * 64 * HDIM);
                    axp += 32; wpp += 32;
                }
                BAR_LGKM();    // LDS writes visible; vmcnt NOT drained
                mfma_phase();
            }
        }

        if (rem) {
            // tail step: scalar masked staging (rare, correctness-first)
            const int jj = t & 31;
            const int rb = t >> 5;          // 0..15
            const int j0 = i + full * 32;
            const bool valid = jj < rem;
            const int j = valid ? (j0 + jj) : i;   // in-bounds col
            const long kc = base + (long)full * 32;
            BAR_PLAIN();
            #pragma unroll
            for (int e = 0; e < 16; ++e) {
                const int m = rb + 16 * e;
                float a = valid ? x[m * DDIM + j] * x[m * DDIM + i] : 0.0f;
                A_lds[m * AST + jj] = f2bf(a);
            }
            #pragma unroll
            for (int e = 0; e < 8; ++e) {
                const int n = rb + 16 * e;
                const long ks = valid ? (kc + jj) : base;
                W_lds[n * WST + jj] = f2bf(W[(long)(n0 + n) * HDIM + ks]);
            }
            BAR_LGKM();
            mfma_phase();
        }
    }

    // plain (non-atomic) partial store: part[s][row][col]
    float* po = part + (long)s * (256 * ODIM);
    #pragma unroll
    for (int fm = 0; fm < 4; ++fm) {
        const int row = wm + fm * 16 + quad * 4;
        #pragma unroll
        for (int fn = 0; fn < 4; ++fn) {
            const int col = n0 + wn + fn * 16 + l15;
            #pragma unroll
            for (int r = 0; r < 4; ++r)
                po[(row + r) * ODIM + col] = acc[fm][fn][r];
        }
    }
}

__global__ __launch_bounds__(256) void reduce_kernel(const float* __restrict__ part,
                                                     float* __restrict__ out) {
    const int gid = blockIdx.x * 256 + threadIdx.x;   // 0..65535 float4s
    floatx4 acc = {};
    #pragma unroll
    for (int sp = 0; sp < NSPLIT; ++sp) {
        floatx4 v = *(const floatx4*)(part + (long)sp * (256 * ODIM) + gid * 4);
        acc += v;
    }
    *(floatx4*)(out + gid * 4) = acc;
}

extern "C" void kernel_launch(void* const* d_in, const int* in_sizes, int n_in,
                              void* d_out, int out_size, void* d_ws, size_t ws_size,
                              hipStream_t stream) {
    const float* x = (const float*)d_in[0];   // (256, 512) fp32
    const float* W = (const float*)d_in[1];   // (1024, 131328) fp32
    float* out  = (float*)d_out;              // (256, 1024) fp32
    float* part = (float*)d_ws;               // 32 x 256 x 1024 fp32 = 32 MB

    hipLaunchKernelGGL(selmul_kernel, dim3(8, NSPLIT), dim3(512), 0, stream, x, W, part);
    hipLaunchKernelGGL(reduce_kernel, dim3(256), dim3(256), 0, stream, part, out);
}